// Round 6
// baseline (1099.459 us; speedup 1.0000x reference)
//
#include <hip/hip_runtime.h>
#include <math.h>

// FusionNeRF round 6: latency-bound fix — more independent barrier domains.
//   BM=32, acc 2x4 (32 AGPR) -> ~105 regs -> launch_bounds(256,4) no-spill
//   -> 4 blocks/CU (16 waves, 4 independent barrier domains, ~50% occ).
//   Ping-pong H0/H1 -> 1 barrier/layer (10 vs 20).
//   nerf_enc uses native __sinf/__cosf.

#define RAYS 2048
#define SAMP 128
#define MTOT (RAYS * SAMP)
#define HD   256
#define BM   32              // samples per block
#define ES   136             // enc LDS stride (fallback kernel)
#define HS   264             // hidden LDS stride (bf16), 256 + 8 pad

#define OUT_RGB   0
#define OUT_DEPTH 6144
#define OUT_W     8192
#define OUT_SW    270336
#define OUT_DW    532480

// bf16 weight workspace offsets (elements)
#define SW0 0
#define SW1 32768
#define SW2 98304
#define SW3 163840
#define SW4 229376
#define DW0 233472
#define DW1 266240
#define DW2 331776
#define DW3 397312
#define DW4 462848
#define WTOT 466944

typedef __attribute__((ext_vector_type(8))) short short8;
typedef __attribute__((ext_vector_type(4))) float f32x4;

__device__ __forceinline__ float sigm(float x) { return 1.0f / (1.0f + expf(-x)); }

__device__ __forceinline__ unsigned bfbits(float f) {  // RNE fp32 -> bf16 bits
    union { float f; unsigned u; } v; v.f = f;
    unsigned r = v.u + 0x7fffu + ((v.u >> 16) & 1u);
    return r >> 16;
}
__device__ __forceinline__ short f2bf(float f) { return (short)bfbits(f); }
__device__ __forceinline__ unsigned pk2(float a, float b) {
    return bfbits(a) | (bfbits(b) << 16);
}

// ---------------- weight prep: W[K][N] fp32 -> Wt[Npad][Kpad] bf16 ----------------
__device__ __forceinline__ void conv1(const float* __restrict__ src, short* __restrict__ dst,
                                      int local, int K, int N, int Kpad) {
    const int n = local / Kpad, k = local - n * Kpad;
    const float v = (k < K && n < N) ? src[k * N + n] : 0.0f;
    dst[local] = f2bf(v);
}

__global__ __launch_bounds__(256)
void prep_weights(const float* sW0, const float* sW1, const float* sW2,
                  const float* sW3, const float* sW4,
                  const float* dW0, const float* dW1, const float* dW2,
                  const float* dW3, const float* dW4, short* __restrict__ dst)
{
    const int idx = blockIdx.x * 256 + threadIdx.x;
    if (idx >= WTOT) return;
    if      (idx < SW1) conv1(sW0, dst + SW0, idx - SW0,  90, 256, 128);
    else if (idx < SW2) conv1(sW1, dst + SW1, idx - SW1, 256, 256, 256);
    else if (idx < SW3) conv1(sW2, dst + SW2, idx - SW2, 256, 256, 256);
    else if (idx < SW4) conv1(sW3, dst + SW3, idx - SW3, 256, 256, 256);
    else if (idx < DW0) conv1(sW4, dst + SW4, idx - SW4, 256,   4, 256);
    else if (idx < DW1) conv1(dW0, dst + DW0, idx - DW0,  99, 256, 128);
    else if (idx < DW2) conv1(dW1, dst + DW1, idx - DW1, 256, 256, 256);
    else if (idx < DW3) conv1(dW2, dst + DW2, idx - DW2, 256, 256, 256);
    else if (idx < DW4) conv1(dW3, dst + DW3, idx - DW3, 256, 256, 256);
    else                conv1(dW4, dst + DW4, idx - DW4, 256,   5, 256);
}

// ---------------- positional encoding (native sin/cos: |err| ~2e-4 << bf16 ulp) ----
__device__ __forceinline__ float encval(int d, int m,
                                        const float* __restrict__ points,
                                        const float* __restrict__ dirsv,
                                        const float* __restrict__ timev)
{
    float v = 0.0f;
    if (d < 3) {
        v = points[m * 3 + d];
    } else if (d < 63) {
        int qq = d - 3;
        const int l = qq / 6, r = qq - l * 6;
        const int c = (r < 3) ? r : r - 3;
        const float x = points[m * 3 + c] * (float)(1 << l);
        v = (r < 3) ? __sinf(x) : __cosf(x);
    } else if (d < 90) {
        int qq = d - 63;
        if (qq < 3) v = dirsv[m * 3 + qq];
        else {
            qq -= 3;
            const int l = qq / 6, r = qq - l * 6;
            const int c = (r < 3) ? r : r - 3;
            const float x = dirsv[m * 3 + c] * (float)(1 << l);
            v = (r < 3) ? __sinf(x) : __cosf(x);
        }
    } else if (d < 99) {
        int qq = d - 90;
        const float t = timev[m];
        if (qq == 0) v = t;
        else {
            qq -= 1;
            const float x = t * (float)(1 << (qq >> 1));
            v = ((qq & 1) == 0) ? __sinf(x) : __cosf(x);
        }
    }
    return v;
}

__global__ __launch_bounds__(256)
void nerf_enc(const float* __restrict__ points, const float* __restrict__ dirsv,
              const float* __restrict__ timev, short* __restrict__ Eg)
{
    const int idx = blockIdx.x * 256 + threadIdx.x;   // one per (m, d-pair)
    if (idx >= MTOT * 64) return;
    const int m = idx >> 6, dp = idx & 63;
    const float v0 = encval(2 * dp,     m, points, dirsv, timev);
    const float v1 = encval(2 * dp + 1, m, points, dirsv, timev);
    *(unsigned*)(Eg + (size_t)m * 128 + 2 * dp) = pk2(v0, v1);
}

// ---------------- epilogue: D^T acc (2x4 tiles) -> O[m][n] packed b64 stores -------
template <bool RELU>
__device__ __forceinline__ void epilogue2(f32x4 acc[2][4], const float* __restrict__ bias,
                                          short* O, int w, int q, int col)
{
    float4 bv[4];
#pragma unroll
    for (int nt = 0; nt < 4; nt++)
        bv[nt] = *(const float4*)(bias + w * 64 + nt * 16 + q * 4);
#pragma unroll
    for (int mt = 0; mt < 2; mt++) {
        short* dst = O + (mt * 16 + col) * HS + w * 64 + q * 4;
#pragma unroll
        for (int nt = 0; nt < 4; nt++) {
            float v0 = acc[mt][nt][0] + bv[nt].x;
            float v1 = acc[mt][nt][1] + bv[nt].y;
            float v2 = acc[mt][nt][2] + bv[nt].z;
            float v3 = acc[mt][nt][3] + bv[nt].w;
            if (RELU) {
                v0 = fmaxf(v0, 0.f); v1 = fmaxf(v1, 0.f);
                v2 = fmaxf(v2, 0.f); v3 = fmaxf(v3, 0.f);
            }
            uint2 p; p.x = pk2(v0, v1); p.y = pk2(v2, v3);
            *(uint2*)(dst + nt * 16) = p;
        }
    }
}

// A (LDS, stride As) -> O (LDS, A != O). No internal barrier; caller syncs.
template <int KSTEPS, bool RELU>
__device__ __forceinline__ void layerL(const short* A, int As,
                                       const short* __restrict__ Wt,
                                       const float* __restrict__ bias,
                                       short* O, int tid)
{
    const int w = tid >> 6, lane = tid & 63, q = lane >> 4, col = lane & 15;
    const int K = KSTEPS * 32;
    f32x4 acc[2][4];
#pragma unroll
    for (int mt = 0; mt < 2; mt++)
#pragma unroll
        for (int nt = 0; nt < 4; nt++) acc[mt][nt] = (f32x4)0.0f;

    const short* wbase = Wt + (size_t)(w * 64) * K + q * 8;
#pragma unroll
    for (int kk = 0; kk < KSTEPS; kk++) {
        short8 a[2], b[4];
#pragma unroll
        for (int mt = 0; mt < 2; mt++)
            a[mt] = *(const short8*)(A + (mt * 16 + col) * As + kk * 32 + q * 8);
#pragma unroll
        for (int nt = 0; nt < 4; nt++)
            b[nt] = *(const short8*)(wbase + (size_t)(nt * 16 + col) * K + kk * 32);
#pragma unroll
        for (int mt = 0; mt < 2; mt++)
#pragma unroll
            for (int nt = 0; nt < 4; nt++)
                acc[mt][nt] = __builtin_amdgcn_mfma_f32_16x16x32_bf16(b[nt], a[mt], acc[mt][nt], 0, 0, 0);
    }
    epilogue2<RELU>(acc, bias, O, w, q, col);
}

// A from global (stride 128, KSTEPS=4) -> O (LDS). No internal barrier.
template <bool RELU>
__device__ __forceinline__ void layerG(const short* __restrict__ Ag,
                                       const short* __restrict__ Wt,
                                       const float* __restrict__ bias,
                                       short* O, int tid)
{
    const int w = tid >> 6, lane = tid & 63, q = lane >> 4, col = lane & 15;
    f32x4 acc[2][4];
#pragma unroll
    for (int mt = 0; mt < 2; mt++)
#pragma unroll
        for (int nt = 0; nt < 4; nt++) acc[mt][nt] = (f32x4)0.0f;

    const short* wbase = Wt + (size_t)(w * 64) * 128 + q * 8;
#pragma unroll
    for (int kk = 0; kk < 4; kk++) {
        short8 a[2], b[4];
#pragma unroll
        for (int mt = 0; mt < 2; mt++)
            a[mt] = *(const short8*)(Ag + (size_t)(mt * 16 + col) * 128 + kk * 32 + q * 8);
#pragma unroll
        for (int nt = 0; nt < 4; nt++)
            b[nt] = *(const short8*)(wbase + (size_t)(nt * 16 + col) * 128 + kk * 32);
#pragma unroll
        for (int mt = 0; mt < 2; mt++)
#pragma unroll
            for (int nt = 0; nt < 4; nt++)
                acc[mt][nt] = __builtin_amdgcn_mfma_f32_16x16x32_bf16(b[nt], a[mt], acc[mt][nt], 0, 0, 0);
    }
    epilogue2<RELU>(acc, bias, O, w, q, col);
}

// head: A[32][256] @ Wt[16][256]^T -> Out[32][NV]; waves 0,1 only (rows w*16..).
template <int NV>
__device__ __forceinline__ void head256(const short* A, int As,
                                        const short* __restrict__ Wt,
                                        const float* __restrict__ bias,
                                        float* Out, int tid)
{
    const int w = tid >> 6, lane = tid & 63, q = lane >> 4, col = lane & 15;
    if (w < 2) {
        f32x4 acc = (f32x4)0.0f;
#pragma unroll
        for (int kk = 0; kk < 8; kk++) {
            short8 a = *(const short8*)(A + (w * 16 + col) * As + kk * 32 + q * 8);
            short8 b = *(const short8*)(Wt + col * 256 + kk * 32 + q * 8);
            acc = __builtin_amdgcn_mfma_f32_16x16x32_bf16(a, b, acc, 0, 0, 0);
        }
        if (col < NV) {
#pragma unroll
            for (int i = 0; i < 4; i++)
                Out[(w * 16 + q * 4 + i) * NV + col] = acc[i] + bias[col];
        }
    }
}

// ---------------- blend epilogue (shared) ----------------
__device__ __forceinline__ void blend_out(const float so[][4], const float dn[][5],
                                          int tid, int m0,
                                          float* o_sigma, float* o_r, float* o_g,
                                          float* o_b, float* o_bw)
{
    if (tid < BM) {
        const int s = tid, m = m0 + s;
        const float bw = sigm(dn[s][4]);
        const float sigma = (1.f - bw) * so[s][0] + bw * dn[s][0];
        const float r  = (1.f - bw) * sigm(so[s][1]) + bw * sigm(dn[s][1]);
        const float gg = (1.f - bw) * sigm(so[s][2]) + bw * sigm(dn[s][2]);
        const float bb = (1.f - bw) * sigm(so[s][3]) + bw * sigm(dn[s][3]);
        o_sigma[m] = sigma; o_r[m] = r; o_g[m] = gg; o_b[m] = bb; o_bw[m] = bw;
    }
}

// ---------------- main MLP kernel: ping-pong H0/H1, 1 barrier per layer ----------
// (256,4): budget 128 regs/wave; footprint ~105 (32 AGPR acc) -> no spill.
__global__ __launch_bounds__(256, 4)
void nerf_mlp_g(const short* __restrict__ Eg, const short* __restrict__ wt,
                const float* __restrict__ sb0, const float* __restrict__ sb1,
                const float* __restrict__ sb2, const float* __restrict__ sb3,
                const float* __restrict__ sb4,
                const float* __restrict__ db0, const float* __restrict__ db1,
                const float* __restrict__ db2, const float* __restrict__ db3,
                const float* __restrict__ db4,
                float* __restrict__ o_sigma, float* __restrict__ o_r,
                float* __restrict__ o_g, float* __restrict__ o_b,
                float* __restrict__ o_bw)
{
    __shared__ short H0[BM][HS];   // 16.9 KB
    __shared__ short H1[BM][HS];   // 16.9 KB
    __shared__ float so[BM][4];
    __shared__ float dn[BM][5];

    const int tid = threadIdx.x;
    const int m0  = blockIdx.x * BM;
    const short* Ag = Eg + (size_t)m0 * 128;

    // static MLP
    layerG<true>(Ag, wt + SW0, sb0, &H0[0][0], tid);                 __syncthreads();
    layerL<8, true>(&H0[0][0], HS, wt + SW1, sb1, &H1[0][0], tid);   __syncthreads();
    layerL<8, true>(&H1[0][0], HS, wt + SW2, sb2, &H0[0][0], tid);   __syncthreads();
    layerL<8, true>(&H0[0][0], HS, wt + SW3, sb3, &H1[0][0], tid);   __syncthreads();
    // static head reads H1 while dynamic L0 writes H0 (disjoint) — one barrier after
    head256<4>(&H1[0][0], HS, wt + SW4, sb4, &so[0][0], tid);
    layerG<true>(Ag, wt + DW0, db0, &H0[0][0], tid);                 __syncthreads();
    layerL<8, true>(&H0[0][0], HS, wt + DW1, db1, &H1[0][0], tid);   __syncthreads();
    layerL<8, true>(&H1[0][0], HS, wt + DW2, db2, &H0[0][0], tid);   __syncthreads();
    layerL<8, true>(&H0[0][0], HS, wt + DW3, db3, &H1[0][0], tid);   __syncthreads();
    head256<5>(&H1[0][0], HS, wt + DW4, db4, &dn[0][0], tid);        __syncthreads();

    blend_out(so, dn, tid, m0, o_sigma, o_r, o_g, o_b, o_bw);
}

// ---------------- fallback MLP kernel: enc computed in LDS ----------------
__global__ __launch_bounds__(256, 4)
void nerf_mlp_l(const float* __restrict__ points, const float* __restrict__ dirsv,
                const float* __restrict__ timev, const short* __restrict__ wt,
                const float* __restrict__ sb0, const float* __restrict__ sb1,
                const float* __restrict__ sb2, const float* __restrict__ sb3,
                const float* __restrict__ sb4,
                const float* __restrict__ db0, const float* __restrict__ db1,
                const float* __restrict__ db2, const float* __restrict__ db3,
                const float* __restrict__ db4,
                float* __restrict__ o_sigma, float* __restrict__ o_r,
                float* __restrict__ o_g, float* __restrict__ o_b,
                float* __restrict__ o_bw)
{
    __shared__ short E[BM][ES];
    __shared__ short H0[BM][HS];
    __shared__ short H1[BM][HS];
    __shared__ float so[BM][4];
    __shared__ float dn[BM][5];

    const int tid = threadIdx.x;
    const int m0  = blockIdx.x * BM;

    for (int idx = tid; idx < BM * 128; idx += 256) {
        const int s = idx >> 7, d = idx & 127;
        E[s][d] = f2bf(encval(d, m0 + s, points, dirsv, timev));
    }
    __syncthreads();

    layerL<4, true>(&E[0][0], ES, wt + SW0, sb0, &H0[0][0], tid);    __syncthreads();
    layerL<8, true>(&H0[0][0], HS, wt + SW1, sb1, &H1[0][0], tid);   __syncthreads();
    layerL<8, true>(&H1[0][0], HS, wt + SW2, sb2, &H0[0][0], tid);   __syncthreads();
    layerL<8, true>(&H0[0][0], HS, wt + SW3, sb3, &H1[0][0], tid);   __syncthreads();
    head256<4>(&H1[0][0], HS, wt + SW4, sb4, &so[0][0], tid);
    layerL<4, true>(&E[0][0], ES, wt + DW0, db0, &H0[0][0], tid);    __syncthreads();
    layerL<8, true>(&H0[0][0], HS, wt + DW1, db1, &H1[0][0], tid);   __syncthreads();
    layerL<8, true>(&H1[0][0], HS, wt + DW2, db2, &H0[0][0], tid);   __syncthreads();
    layerL<8, true>(&H0[0][0], HS, wt + DW3, db3, &H1[0][0], tid);   __syncthreads();
    head256<5>(&H1[0][0], HS, wt + DW4, db4, &dn[0][0], tid);        __syncthreads();

    blend_out(so, dn, tid, m0, o_sigma, o_r, o_g, o_b, o_bw);
}

// ---------------- compositing: one wave per ray, shuffle scan ----------------
__global__ __launch_bounds__(256)
void nerf_comp(const float* __restrict__ zv,
               const float* __restrict__ o_sigma, const float* __restrict__ o_r,
               const float* __restrict__ o_g, const float* __restrict__ o_b,
               const float* __restrict__ o_bw, float* __restrict__ out)
{
    const int ray  = blockIdx.x * 4 + (threadIdx.x >> 6);
    const int lane = threadIdx.x & 63;
    const int base = ray * SAMP;
    const int s0 = 2 * lane, s1 = s0 + 1;

    const float z0 = zv[base + s0];
    const float z1 = zv[base + s1];
    const float z2 = (lane < 63) ? zv[base + s1 + 1] : 0.0f;
    const float d0 = z1 - z0;
    const float d1 = (lane < 63) ? (z2 - z1) : 1e10f;

    const float sg0 = o_sigma[base + s0], sg1 = o_sigma[base + s1];
    const float a0 = 1.0f - expf(-sg0 * d0);
    const float a1 = 1.0f - expf(-sg1 * d1);
    const float f0 = 1.0f - a0 + 1e-10f;
    const float f1 = 1.0f - a1 + 1e-10f;

    float incl = f0 * f1;
#pragma unroll
    for (int dlt = 1; dlt < 64; dlt <<= 1) {
        const float t = __shfl_up(incl, dlt);
        if (lane >= dlt) incl *= t;
    }
    float ex = __shfl_up(incl, 1);
    if (lane == 0) ex = 1.0f;

    const float t0 = ex;
    const float t1 = ex * f0;
    const float w0 = a0 * t0, w1 = a1 * t1;

    const float bw0 = o_bw[base + s0], bw1 = o_bw[base + s1];
    out[OUT_W  + base + s0] = w0;               out[OUT_W  + base + s1] = w1;
    out[OUT_SW + base + s0] = (1.f - bw0) * w0; out[OUT_SW + base + s1] = (1.f - bw1) * w1;
    out[OUT_DW + base + s0] = bw0 * w0;         out[OUT_DW + base + s1] = bw1 * w1;

    float pr = w0 * o_r[base + s0] + w1 * o_r[base + s1];
    float pg = w0 * o_g[base + s0] + w1 * o_g[base + s1];
    float pb = w0 * o_b[base + s0] + w1 * o_b[base + s1];
    float pd = w0 * z0 + w1 * z1;
#pragma unroll
    for (int dlt = 32; dlt >= 1; dlt >>= 1) {
        pr += __shfl_down(pr, dlt);
        pg += __shfl_down(pg, dlt);
        pb += __shfl_down(pb, dlt);
        pd += __shfl_down(pd, dlt);
    }
    if (lane == 0) {
        out[OUT_RGB + ray * 3 + 0] = pr;
        out[OUT_RGB + ray * 3 + 1] = pg;
        out[OUT_RGB + ray * 3 + 2] = pb;
        out[OUT_DEPTH + ray] = pd;
    }
}

extern "C" void kernel_launch(void* const* d_in, const int* in_sizes, int n_in,
                              void* d_out, int out_size, void* d_ws, size_t ws_size,
                              hipStream_t stream)
{
    const float* points = (const float*)d_in[0];
    const float* dirsv  = (const float*)d_in[1];
    const float* zvals  = (const float*)d_in[2];
    const float* timev  = (const float*)d_in[3];

    const float *sW[5], *sb[5], *dW[5], *db[5];
    if (in_sizes[6] == 99 * 256) {
        for (int i = 0; i < 5; i++) {   // interleaved (sW_i, sb_i, dW_i, db_i)
            sW[i] = (const float*)d_in[4 + 4 * i + 0];
            sb[i] = (const float*)d_in[4 + 4 * i + 1];
            dW[i] = (const float*)d_in[4 + 4 * i + 2];
            db[i] = (const float*)d_in[4 + 4 * i + 3];
        }
    } else {
        for (int i = 0; i < 5; i++) {   // all static then all dynamic
            sW[i] = (const float*)d_in[4 + 2 * i + 0];
            sb[i] = (const float*)d_in[4 + 2 * i + 1];
            dW[i] = (const float*)d_in[14 + 2 * i + 0];
            db[i] = (const float*)d_in[14 + 2 * i + 1];
        }
    }

    // ws layout: wt bf16 weights | Eg bf16 [MTOT][128] | 5 fp32 per-sample arrays
    const size_t wt_bytes = (size_t)WTOT * 2;
    const size_t eg_bytes = (size_t)MTOT * 128 * 2;
    const size_t f_bytes  = (size_t)MTOT * 5 * 4;
    const bool   big_ws   = ws_size >= wt_bytes + eg_bytes + f_bytes;

    short* wt = (short*)d_ws;
    short* Eg = (short*)((char*)d_ws + wt_bytes);
    float* ws = (float*)((char*)d_ws + wt_bytes + (big_ws ? eg_bytes : 0));
    float* o_sigma = ws;
    float* o_r  = ws + (size_t)MTOT * 1;
    float* o_g  = ws + (size_t)MTOT * 2;
    float* o_b  = ws + (size_t)MTOT * 3;
    float* o_bw = ws + (size_t)MTOT * 4;

    prep_weights<<<(WTOT + 255) / 256, 256, 0, stream>>>(
        sW[0], sW[1], sW[2], sW[3], sW[4], dW[0], dW[1], dW[2], dW[3], dW[4], wt);

    if (big_ws) {
        nerf_enc<<<MTOT * 64 / 256, 256, 0, stream>>>(points, dirsv, timev, Eg);
        nerf_mlp_g<<<MTOT / BM, 256, 0, stream>>>(Eg, wt,
            sb[0], sb[1], sb[2], sb[3], sb[4], db[0], db[1], db[2], db[3], db[4],
            o_sigma, o_r, o_g, o_b, o_bw);
    } else {
        nerf_mlp_l<<<MTOT / BM, 256, 0, stream>>>(points, dirsv, timev, wt,
            sb[0], sb[1], sb[2], sb[3], sb[4], db[0], db[1], db[2], db[3], db[4],
            o_sigma, o_r, o_g, o_b, o_bw);
    }

    nerf_comp<<<RAYS / 4, 256, 0, stream>>>(zvals, o_sigma, o_r, o_g, o_b, o_bw,
                                            (float*)d_out);
}

// Round 7
// 735.711 us; speedup vs baseline: 1.4944x; 1.4944x over previous
//
#include <hip/hip_runtime.h>
#include <math.h>

// FusionNeRF round 7: register-resident weight slices.
//   R6 isolated the bottleneck: per-wave interleaved L2 weight loads
//   (latency-bound, ~6 in flight). New structure: 512-thr blocks, 8 waves,
//   each wave owns a 32-neuron slice; the full K-panel (16 KB = 64 VGPR) is
//   burst-preloaded at layer start (16 independent dwordx4 -> vmcnt(N)
//   pipeline), K-loop = LDS a-reads + MFMA from regs. acc 32 AGPR,
//   launch_bounds(512,4), ping-pong H0/H1, 9 barriers/block, 2 blocks/CU.

#define RAYS 2048
#define SAMP 128
#define MTOT (RAYS * SAMP)
#define HD   256
#define BM   64              // samples per block
#define ES   136             // enc LDS stride (fallback kernel)
#define HS   264             // hidden LDS stride (bf16), 256 + 8 pad

#define OUT_RGB   0
#define OUT_DEPTH 6144
#define OUT_W     8192
#define OUT_SW    270336
#define OUT_DW    532480

// bf16 weight workspace offsets (elements)
#define SW0 0
#define SW1 32768
#define SW2 98304
#define SW3 163840
#define SW4 229376
#define DW0 233472
#define DW1 266240
#define DW2 331776
#define DW3 397312
#define DW4 462848
#define WTOT 466944

typedef __attribute__((ext_vector_type(8))) short short8;
typedef __attribute__((ext_vector_type(4))) float f32x4;

__device__ __forceinline__ float sigm(float x) { return 1.0f / (1.0f + expf(-x)); }

__device__ __forceinline__ unsigned bfbits(float f) {  // RNE fp32 -> bf16 bits
    union { float f; unsigned u; } v; v.f = f;
    unsigned r = v.u + 0x7fffu + ((v.u >> 16) & 1u);
    return r >> 16;
}
__device__ __forceinline__ short f2bf(float f) { return (short)bfbits(f); }
__device__ __forceinline__ unsigned pk2(float a, float b) {
    return bfbits(a) | (bfbits(b) << 16);
}

// ---------------- weight prep: W[K][N] fp32 -> Wt[Npad][Kpad] bf16 ----------------
__device__ __forceinline__ void conv1(const float* __restrict__ src, short* __restrict__ dst,
                                      int local, int K, int N, int Kpad) {
    const int n = local / Kpad, k = local - n * Kpad;
    const float v = (k < K && n < N) ? src[k * N + n] : 0.0f;
    dst[local] = f2bf(v);
}

__global__ __launch_bounds__(256)
void prep_weights(const float* sW0, const float* sW1, const float* sW2,
                  const float* sW3, const float* sW4,
                  const float* dW0, const float* dW1, const float* dW2,
                  const float* dW3, const float* dW4, short* __restrict__ dst)
{
    const int idx = blockIdx.x * 256 + threadIdx.x;
    if (idx >= WTOT) return;
    if      (idx < SW1) conv1(sW0, dst + SW0, idx - SW0,  90, 256, 128);
    else if (idx < SW2) conv1(sW1, dst + SW1, idx - SW1, 256, 256, 256);
    else if (idx < SW3) conv1(sW2, dst + SW2, idx - SW2, 256, 256, 256);
    else if (idx < SW4) conv1(sW3, dst + SW3, idx - SW3, 256, 256, 256);
    else if (idx < DW0) conv1(sW4, dst + SW4, idx - SW4, 256,   4, 256);
    else if (idx < DW1) conv1(dW0, dst + DW0, idx - DW0,  99, 256, 128);
    else if (idx < DW2) conv1(dW1, dst + DW1, idx - DW1, 256, 256, 256);
    else if (idx < DW3) conv1(dW2, dst + DW2, idx - DW2, 256, 256, 256);
    else if (idx < DW4) conv1(dW3, dst + DW3, idx - DW3, 256, 256, 256);
    else                conv1(dW4, dst + DW4, idx - DW4, 256,   5, 256);
}

// ---------------- positional encoding (native sin/cos, d-uniform branches) -------
__device__ __forceinline__ float encval(int d, int m,
                                        const float* __restrict__ points,
                                        const float* __restrict__ dirsv,
                                        const float* __restrict__ timev)
{
    float v = 0.0f;
    if (d < 3) {
        v = points[m * 3 + d];
    } else if (d < 63) {
        int qq = d - 3;
        const int l = qq / 6, r = qq - l * 6;
        const int c = (r < 3) ? r : r - 3;
        const float x = points[m * 3 + c] * (float)(1 << l);
        v = (r < 3) ? __sinf(x) : __cosf(x);
    } else if (d < 90) {
        int qq = d - 63;
        if (qq < 3) v = dirsv[m * 3 + qq];
        else {
            qq -= 3;
            const int l = qq / 6, r = qq - l * 6;
            const int c = (r < 3) ? r : r - 3;
            const float x = dirsv[m * 3 + c] * (float)(1 << l);
            v = (r < 3) ? __sinf(x) : __cosf(x);
        }
    } else if (d < 99) {
        int qq = d - 90;
        const float t = timev[m];
        if (qq == 0) v = t;
        else {
            qq -= 1;
            const float x = t * (float)(1 << (qq >> 1));
            v = ((qq & 1) == 0) ? __sinf(x) : __cosf(x);
        }
    }
    return v;
}

// 64 samples/block; wave = 64 lanes all computing the SAME d (uniform branches),
// different samples. LDS-staged, coalesced b128 writeout.
__global__ __launch_bounds__(256)
void nerf_enc(const float* __restrict__ points, const float* __restrict__ dirsv,
              const float* __restrict__ timev, short* __restrict__ Eg)
{
    __shared__ short Et[64][128];   // 16 KB, rows contiguous
    const int tid = threadIdx.x;
    const int s   = tid & 63;       // sample lane
    const int dc  = tid >> 6;       // d-chunk (wave id): d in [32dc, 32dc+32)
    const int m   = blockIdx.x * 64 + s;
#pragma unroll
    for (int j = 0; j < 32; j++) {
        const int d = dc * 32 + j;
        Et[s][d] = f2bf(encval(d, m, points, dirsv, timev));
    }
    __syncthreads();
    short* dst = Eg + (size_t)blockIdx.x * 64 * 128;
    const short* src = &Et[0][0];
#pragma unroll
    for (int i = 0; i < 4; i++) {
        const int e = (tid + i * 256) * 8;
        *(short8*)(dst + e) = *(const short8*)(src + e);
    }
}

// ---------------- register-preload MFMA layer (main kernel) ----------------
// Wave owns 32 output neurons. Weight panel Ws[32][K] burst-loaded into
// w[2*KSTEPS] regs, then K-loop reads only LDS a-frags. D^T epilogue ->
// packed b64 LDS stores at Ocol (= O + nbase). No internal barrier.
template <int KSTEPS, bool RELU>
__device__ __forceinline__ void layerRL(const short* A,
                                        const short* __restrict__ Ws,
                                        const float* __restrict__ biasN,
                                        short* Ocol, int c, int q)
{
    const int K = KSTEPS * 32;
    short8 w[KSTEPS * 2];
#pragma unroll
    for (int kk = 0; kk < KSTEPS; kk++)
#pragma unroll
        for (int nt = 0; nt < 2; nt++)
            w[kk * 2 + nt] = *(const short8*)(Ws + (size_t)(nt * 16 + c) * K + kk * 32 + q * 8);

    f32x4 acc[4][2];
#pragma unroll
    for (int mt = 0; mt < 4; mt++)
#pragma unroll
        for (int nt = 0; nt < 2; nt++) acc[mt][nt] = (f32x4)0.0f;

#pragma unroll
    for (int kk = 0; kk < KSTEPS; kk++) {
        short8 a[4];
#pragma unroll
        for (int mt = 0; mt < 4; mt++)
            a[mt] = *(const short8*)(A + (mt * 16 + c) * HS + kk * 32 + q * 8);
#pragma unroll
        for (int mt = 0; mt < 4; mt++)
#pragma unroll
            for (int nt = 0; nt < 2; nt++)
                acc[mt][nt] = __builtin_amdgcn_mfma_f32_16x16x32_bf16(w[kk * 2 + nt], a[mt], acc[mt][nt], 0, 0, 0);
    }

    float4 bv[2];
#pragma unroll
    for (int nt = 0; nt < 2; nt++) bv[nt] = *(const float4*)(biasN + nt * 16 + q * 4);
#pragma unroll
    for (int mt = 0; mt < 4; mt++) {
        short* dst = Ocol + (mt * 16 + c) * HS + q * 4;
#pragma unroll
        for (int nt = 0; nt < 2; nt++) {
            float v0 = acc[mt][nt][0] + bv[nt].x;
            float v1 = acc[mt][nt][1] + bv[nt].y;
            float v2 = acc[mt][nt][2] + bv[nt].z;
            float v3 = acc[mt][nt][3] + bv[nt].w;
            if (RELU) {
                v0 = fmaxf(v0, 0.f); v1 = fmaxf(v1, 0.f);
                v2 = fmaxf(v2, 0.f); v3 = fmaxf(v3, 0.f);
            }
            uint2 p; p.x = pk2(v0, v1); p.y = pk2(v2, v3);
            *(uint2*)(dst + nt * 16) = p;
        }
    }
}

// same but A from global (stride 128), KSTEPS=4
template <bool RELU>
__device__ __forceinline__ void layerRG(const short* __restrict__ Ag,
                                        const short* __restrict__ Ws,
                                        const float* __restrict__ biasN,
                                        short* Ocol, int c, int q)
{
    short8 w[8];
#pragma unroll
    for (int kk = 0; kk < 4; kk++)
#pragma unroll
        for (int nt = 0; nt < 2; nt++)
            w[kk * 2 + nt] = *(const short8*)(Ws + (size_t)(nt * 16 + c) * 128 + kk * 32 + q * 8);

    f32x4 acc[4][2];
#pragma unroll
    for (int mt = 0; mt < 4; mt++)
#pragma unroll
        for (int nt = 0; nt < 2; nt++) acc[mt][nt] = (f32x4)0.0f;

#pragma unroll
    for (int kk = 0; kk < 4; kk++) {
        short8 a[4];
#pragma unroll
        for (int mt = 0; mt < 4; mt++)
            a[mt] = *(const short8*)(Ag + (size_t)(mt * 16 + c) * 128 + kk * 32 + q * 8);
#pragma unroll
        for (int mt = 0; mt < 4; mt++)
#pragma unroll
            for (int nt = 0; nt < 2; nt++)
                acc[mt][nt] = __builtin_amdgcn_mfma_f32_16x16x32_bf16(w[kk * 2 + nt], a[mt], acc[mt][nt], 0, 0, 0);
    }

    float4 bv[2];
#pragma unroll
    for (int nt = 0; nt < 2; nt++) bv[nt] = *(const float4*)(biasN + nt * 16 + q * 4);
#pragma unroll
    for (int mt = 0; mt < 4; mt++) {
        short* dst = Ocol + (mt * 16 + c) * HS + q * 4;
#pragma unroll
        for (int nt = 0; nt < 2; nt++) {
            float v0 = acc[mt][nt][0] + bv[nt].x;
            float v1 = acc[mt][nt][1] + bv[nt].y;
            float v2 = acc[mt][nt][2] + bv[nt].z;
            float v3 = acc[mt][nt][3] + bv[nt].w;
            if (RELU) {
                v0 = fmaxf(v0, 0.f); v1 = fmaxf(v1, 0.f);
                v2 = fmaxf(v2, 0.f); v3 = fmaxf(v3, 0.f);
            }
            uint2 p; p.x = pk2(v0, v1); p.y = pk2(v2, v3);
            *(uint2*)(dst + nt * 16) = p;
        }
    }
}

// head: A[64][256] @ Wt[16][256]^T -> Out[64][NV]; waves 0..3 (rows w*16..).
template <int NV>
__device__ __forceinline__ void head256(const short* A, int As,
                                        const short* __restrict__ Wt,
                                        const float* __restrict__ bias,
                                        float* Out, int tid)
{
    const int w = tid >> 6, lane = tid & 63, q = lane >> 4, col = lane & 15;
    if (w < 4) {
        f32x4 acc = (f32x4)0.0f;
#pragma unroll
        for (int kk = 0; kk < 8; kk++) {
            short8 a = *(const short8*)(A + (w * 16 + col) * As + kk * 32 + q * 8);
            short8 b = *(const short8*)(Wt + col * 256 + kk * 32 + q * 8);
            acc = __builtin_amdgcn_mfma_f32_16x16x32_bf16(a, b, acc, 0, 0, 0);
        }
        if (col < NV) {
#pragma unroll
            for (int i = 0; i < 4; i++)
                Out[(w * 16 + q * 4 + i) * NV + col] = acc[i] + bias[col];
        }
    }
}

__device__ __forceinline__ void blend_out(const float so[][4], const float dn[][5],
                                          int tid, int m0,
                                          float* o_sigma, float* o_r, float* o_g,
                                          float* o_b, float* o_bw)
{
    if (tid < BM) {
        const int s = tid, m = m0 + s;
        const float bw = sigm(dn[s][4]);
        const float sigma = (1.f - bw) * so[s][0] + bw * dn[s][0];
        const float r  = (1.f - bw) * sigm(so[s][1]) + bw * sigm(dn[s][1]);
        const float gg = (1.f - bw) * sigm(so[s][2]) + bw * sigm(dn[s][2]);
        const float bb = (1.f - bw) * sigm(so[s][3]) + bw * sigm(dn[s][3]);
        o_sigma[m] = sigma; o_r[m] = r; o_g[m] = gg; o_b[m] = bb; o_bw[m] = bw;
    }
}

// ---------------- main MLP kernel: 512 threads, 8 waves, ping-pong H0/H1 --------
__global__ __launch_bounds__(512, 4)
void nerf_mlp_g(const short* __restrict__ Eg, const short* __restrict__ wt,
                const float* __restrict__ sb0, const float* __restrict__ sb1,
                const float* __restrict__ sb2, const float* __restrict__ sb3,
                const float* __restrict__ sb4,
                const float* __restrict__ db0, const float* __restrict__ db1,
                const float* __restrict__ db2, const float* __restrict__ db3,
                const float* __restrict__ db4,
                float* __restrict__ o_sigma, float* __restrict__ o_r,
                float* __restrict__ o_g, float* __restrict__ o_b,
                float* __restrict__ o_bw)
{
    __shared__ short H0[BM][HS];   // 33.8 KB
    __shared__ short H1[BM][HS];   // 33.8 KB
    __shared__ float so[BM][4];
    __shared__ float dn[BM][5];

    const int tid  = threadIdx.x;
    const int w8   = tid >> 6;          // wave 0..7 -> 32-neuron slice
    const int lane = tid & 63;
    const int q    = lane >> 4, c = lane & 15;
    const int nb   = w8 * 32;
    const int m0   = blockIdx.x * BM;
    const short* Ag = Eg + (size_t)m0 * 128;
    short* h0 = &H0[0][0];
    short* h1 = &H1[0][0];

    // static MLP
    layerRG<true>(Ag, wt + SW0 + (size_t)nb * 128, sb0 + nb, h0 + nb, c, q);  __syncthreads();
    layerRL<8, true>(h0, wt + SW1 + (size_t)nb * 256, sb1 + nb, h1 + nb, c, q); __syncthreads();
    layerRL<8, true>(h1, wt + SW2 + (size_t)nb * 256, sb2 + nb, h0 + nb, c, q); __syncthreads();
    layerRL<8, true>(h0, wt + SW3 + (size_t)nb * 256, sb3 + nb, h1 + nb, c, q); __syncthreads();
    // static head reads H1 (waves 0..3) while dynamic L0 writes H0 — disjoint
    head256<4>(h1, HS, wt + SW4, sb4, &so[0][0], tid);
    layerRG<true>(Ag, wt + DW0 + (size_t)nb * 128, db0 + nb, h0 + nb, c, q);  __syncthreads();
    layerRL<8, true>(h0, wt + DW1 + (size_t)nb * 256, db1 + nb, h1 + nb, c, q); __syncthreads();
    layerRL<8, true>(h1, wt + DW2 + (size_t)nb * 256, db2 + nb, h0 + nb, c, q); __syncthreads();
    layerRL<8, true>(h0, wt + DW3 + (size_t)nb * 256, db3 + nb, h1 + nb, c, q); __syncthreads();
    head256<5>(h1, HS, wt + DW4, db4, &dn[0][0], tid);                        __syncthreads();

    blend_out(so, dn, tid, m0, o_sigma, o_r, o_g, o_b, o_bw);
}

// ---------------- fallback (small ws): R5-style 256-thread, enc in LDS ----------
template <bool RELU>
__device__ __forceinline__ void epi44(f32x4 acc[4][4], const float* __restrict__ bias,
                                      short* O, int w, int q, int col)
{
    float4 bv[4];
#pragma unroll
    for (int nt = 0; nt < 4; nt++)
        bv[nt] = *(const float4*)(bias + w * 64 + nt * 16 + q * 4);
#pragma unroll
    for (int mt = 0; mt < 4; mt++) {
        short* dst = O + (mt * 16 + col) * HS + w * 64 + q * 4;
#pragma unroll
        for (int nt = 0; nt < 4; nt++) {
            float v0 = acc[mt][nt][0] + bv[nt].x;
            float v1 = acc[mt][nt][1] + bv[nt].y;
            float v2 = acc[mt][nt][2] + bv[nt].z;
            float v3 = acc[mt][nt][3] + bv[nt].w;
            if (RELU) {
                v0 = fmaxf(v0, 0.f); v1 = fmaxf(v1, 0.f);
                v2 = fmaxf(v2, 0.f); v3 = fmaxf(v3, 0.f);
            }
            uint2 p; p.x = pk2(v0, v1); p.y = pk2(v2, v3);
            *(uint2*)(dst + nt * 16) = p;
        }
    }
}

template <int KSTEPS, bool RELU>
__device__ __forceinline__ void layerL44(const short* A, int As,
                                         const short* __restrict__ Wt,
                                         const float* __restrict__ bias,
                                         short* O, int tid)
{
    const int w = tid >> 6, lane = tid & 63, q = lane >> 4, col = lane & 15;
    const int K = KSTEPS * 32;
    f32x4 acc[4][4];
#pragma unroll
    for (int mt = 0; mt < 4; mt++)
#pragma unroll
        for (int nt = 0; nt < 4; nt++) acc[mt][nt] = (f32x4)0.0f;

    const short* wbase = Wt + (size_t)(w * 64) * K + q * 8;
#pragma unroll
    for (int kk = 0; kk < KSTEPS; kk++) {
        short8 a[4], b[4];
#pragma unroll
        for (int mt = 0; mt < 4; mt++)
            a[mt] = *(const short8*)(A + (mt * 16 + col) * As + kk * 32 + q * 8);
#pragma unroll
        for (int nt = 0; nt < 4; nt++)
            b[nt] = *(const short8*)(wbase + (size_t)(nt * 16 + col) * K + kk * 32);
#pragma unroll
        for (int mt = 0; mt < 4; mt++)
#pragma unroll
            for (int nt = 0; nt < 4; nt++)
                acc[mt][nt] = __builtin_amdgcn_mfma_f32_16x16x32_bf16(b[nt], a[mt], acc[mt][nt], 0, 0, 0);
    }
    __syncthreads();
    epi44<RELU>(acc, bias, O, w, q, col);
    __syncthreads();
}

__global__ __launch_bounds__(256, 3)
void nerf_mlp_l(const float* __restrict__ points, const float* __restrict__ dirsv,
                const float* __restrict__ timev, const short* __restrict__ wt,
                const float* __restrict__ sb0, const float* __restrict__ sb1,
                const float* __restrict__ sb2, const float* __restrict__ sb3,
                const float* __restrict__ sb4,
                const float* __restrict__ db0, const float* __restrict__ db1,
                const float* __restrict__ db2, const float* __restrict__ db3,
                const float* __restrict__ db4,
                float* __restrict__ o_sigma, float* __restrict__ o_r,
                float* __restrict__ o_g, float* __restrict__ o_b,
                float* __restrict__ o_bw)
{
    __shared__ short E[BM][ES];
    __shared__ short Hb[BM][HS];
    __shared__ float so[BM][4];
    __shared__ float dn[BM][5];

    const int tid = threadIdx.x;
    const int m0  = blockIdx.x * BM;

    for (int idx = tid; idx < BM * 128; idx += 256) {
        const int s = idx >> 7, d = idx & 127;
        E[s][d] = f2bf(encval(d, m0 + s, points, dirsv, timev));
    }
    __syncthreads();

    layerL44<4, true>(&E[0][0], ES, wt + SW0, sb0, &Hb[0][0], tid);
    layerL44<8, true>(&Hb[0][0], HS, wt + SW1, sb1, &Hb[0][0], tid);
    layerL44<8, true>(&Hb[0][0], HS, wt + SW2, sb2, &Hb[0][0], tid);
    layerL44<8, true>(&Hb[0][0], HS, wt + SW3, sb3, &Hb[0][0], tid);
    head256<4>(&Hb[0][0], HS, wt + SW4, sb4, &so[0][0], tid);

    layerL44<4, true>(&E[0][0], ES, wt + DW0, db0, &Hb[0][0], tid);
    layerL44<8, true>(&Hb[0][0], HS, wt + DW1, db1, &Hb[0][0], tid);
    layerL44<8, true>(&Hb[0][0], HS, wt + DW2, db2, &Hb[0][0], tid);
    layerL44<8, true>(&Hb[0][0], HS, wt + DW3, db3, &Hb[0][0], tid);
    head256<5>(&Hb[0][0], HS, wt + DW4, db4, &dn[0][0], tid);
    __syncthreads();

    blend_out(so, dn, tid, m0, o_sigma, o_r, o_g, o_b, o_bw);
}

// ---------------- compositing: one wave per ray, shuffle scan ----------------
__global__ __launch_bounds__(256)
void nerf_comp(const float* __restrict__ zv,
               const float* __restrict__ o_sigma, const float* __restrict__ o_r,
               const float* __restrict__ o_g, const float* __restrict__ o_b,
               const float* __restrict__ o_bw, float* __restrict__ out)
{
    const int ray  = blockIdx.x * 4 + (threadIdx.x >> 6);
    const int lane = threadIdx.x & 63;
    const int base = ray * SAMP;
    const int s0 = 2 * lane, s1 = s0 + 1;

    const float z0 = zv[base + s0];
    const float z1 = zv[base + s1];
    const float z2 = (lane < 63) ? zv[base + s1 + 1] : 0.0f;
    const float d0 = z1 - z0;
    const float d1 = (lane < 63) ? (z2 - z1) : 1e10f;

    const float sg0 = o_sigma[base + s0], sg1 = o_sigma[base + s1];
    const float a0 = 1.0f - expf(-sg0 * d0);
    const float a1 = 1.0f - expf(-sg1 * d1);
    const float f0 = 1.0f - a0 + 1e-10f;
    const float f1 = 1.0f - a1 + 1e-10f;

    float incl = f0 * f1;
#pragma unroll
    for (int dlt = 1; dlt < 64; dlt <<= 1) {
        const float t = __shfl_up(incl, dlt);
        if (lane >= dlt) incl *= t;
    }
    float ex = __shfl_up(incl, 1);
    if (lane == 0) ex = 1.0f;

    const float t0 = ex;
    const float t1 = ex * f0;
    const float w0 = a0 * t0, w1 = a1 * t1;

    const float bw0 = o_bw[base + s0], bw1 = o_bw[base + s1];
    out[OUT_W  + base + s0] = w0;               out[OUT_W  + base + s1] = w1;
    out[OUT_SW + base + s0] = (1.f - bw0) * w0; out[OUT_SW + base + s1] = (1.f - bw1) * w1;
    out[OUT_DW + base + s0] = bw0 * w0;         out[OUT_DW + base + s1] = bw1 * w1;

    float pr = w0 * o_r[base + s0] + w1 * o_r[base + s1];
    float pg = w0 * o_g[base + s0] + w1 * o_g[base + s1];
    float pb = w0 * o_b[base + s0] + w1 * o_b[base + s1];
    float pd = w0 * z0 + w1 * z1;
#pragma unroll
    for (int dlt = 32; dlt >= 1; dlt >>= 1) {
        pr += __shfl_down(pr, dlt);
        pg += __shfl_down(pg, dlt);
        pb += __shfl_down(pb, dlt);
        pd += __shfl_down(pd, dlt);
    }
    if (lane == 0) {
        out[OUT_RGB + ray * 3 + 0] = pr;
        out[OUT_RGB + ray * 3 + 1] = pg;
        out[OUT_RGB + ray * 3 + 2] = pb;
        out[OUT_DEPTH + ray] = pd;
    }
}

extern "C" void kernel_launch(void* const* d_in, const int* in_sizes, int n_in,
                              void* d_out, int out_size, void* d_ws, size_t ws_size,
                              hipStream_t stream)
{
    const float* points = (const float*)d_in[0];
    const float* dirsv  = (const float*)d_in[1];
    const float* zvals  = (const float*)d_in[2];
    const float* timev  = (const float*)d_in[3];

    const float *sW[5], *sb[5], *dW[5], *db[5];
    if (in_sizes[6] == 99 * 256) {
        for (int i = 0; i < 5; i++) {   // interleaved (sW_i, sb_i, dW_i, db_i)
            sW[i] = (const float*)d_in[4 + 4 * i + 0];
            sb[i] = (const float*)d_in[4 + 4 * i + 1];
            dW[i] = (const float*)d_in[4 + 4 * i + 2];
            db[i] = (const float*)d_in[4 + 4 * i + 3];
        }
    } else {
        for (int i = 0; i < 5; i++) {   // all static then all dynamic
            sW[i] = (const float*)d_in[4 + 2 * i + 0];
            sb[i] = (const float*)d_in[4 + 2 * i + 1];
            dW[i] = (const float*)d_in[14 + 2 * i + 0];
            db[i] = (const float*)d_in[14 + 2 * i + 1];
        }
    }

    // ws layout: wt bf16 weights | Eg bf16 [MTOT][128] | 5 fp32 per-sample arrays
    const size_t wt_bytes = (size_t)WTOT * 2;
    const size_t eg_bytes = (size_t)MTOT * 128 * 2;
    const size_t f_bytes  = (size_t)MTOT * 5 * 4;
    const bool   big_ws   = ws_size >= wt_bytes + eg_bytes + f_bytes;

    short* wt = (short*)d_ws;
    short* Eg = (short*)((char*)d_ws + wt_bytes);
    float* ws = (float*)((char*)d_ws + wt_bytes + (big_ws ? eg_bytes : 0));
    float* o_sigma = ws;
    float* o_r  = ws + (size_t)MTOT * 1;
    float* o_g  = ws + (size_t)MTOT * 2;
    float* o_b  = ws + (size_t)MTOT * 3;
    float* o_bw = ws + (size_t)MTOT * 4;

    prep_weights<<<(WTOT + 255) / 256, 256, 0, stream>>>(
        sW[0], sW[1], sW[2], sW[3], sW[4], dW[0], dW[1], dW[2], dW[3], dW[4], wt);

    if (big_ws) {
        nerf_enc<<<MTOT / 64, 256, 0, stream>>>(points, dirsv, timev, Eg);
        nerf_mlp_g<<<MTOT / BM, 512, 0, stream>>>(Eg, wt,
            sb[0], sb[1], sb[2], sb[3], sb[4], db[0], db[1], db[2], db[3], db[4],
            o_sigma, o_r, o_g, o_b, o_bw);
    } else {
        nerf_mlp_l<<<MTOT / BM, 256, 0, stream>>>(points, dirsv, timev, wt,
            sb[0], sb[1], sb[2], sb[3], sb[4], db[0], db[1], db[2], db[3], db[4],
            o_sigma, o_r, o_g, o_b, o_bw);
    }

    nerf_comp<<<RAYS / 4, 256, 0, stream>>>(zvals, o_sigma, o_r, o_g, o_b, o_bw,
                                            (float*)d_out);
}